// Round 5
// baseline (338.775 us; speedup 1.0000x reference)
//
#include <hip/hip_runtime.h>
#include <cstddef>
#include <cstdint>

#define Bc 2
#define Sc 2048
#define Ec 1024
#define Hc 16
#define HDc 64
#define DFFc 4096
#define ROWS (Bc * Sc)  // 4096

typedef _Float16 half8v __attribute__((ext_vector_type(8)));  // 8 fp16 (4 VGPR)
typedef _Float16 half4v __attribute__((ext_vector_type(4)));
typedef float f32x4 __attribute__((ext_vector_type(4)));      // MFMA C/D frag
typedef _Float16 h16;

// async global->LDS, 16B per lane. LDS dest must be wave-uniform base + lane*16.
__device__ inline void gld_lds16(const void* g, void* l) {
    __builtin_amdgcn_global_load_lds(
        (const __attribute__((address_space(1))) void*)g,
        (__attribute__((address_space(3))) void*)l, 16, 0, 0);
}

// gelu_new via sigmoid identity: 0.5x(1+tanh(z)) == x*sigmoid(2z).
__device__ inline float gelu_new(float x) {
    float x2 = x * x;
    float u = x * fmaf(0.07135481627362f, x2, 1.5957691216057308f);
    return x / (1.0f + __expf(-u));
}

// ---------------------------------------------------------------------------
// fused fp32 -> fp16 convert for all 4 weights (outputs contiguous in ws)
// ---------------------------------------------------------------------------
__global__ __launch_bounds__(256) void cvt4_kernel(
    const float* __restrict__ a,  // 3M elems  -> blocks [0, 3072)
    const float* __restrict__ b,  // 1M elems  -> blocks [3072, 4096)
    const float* __restrict__ c,  // 4M elems  -> blocks [4096, 8192)
    const float* __restrict__ d,  // 4M elems  -> blocks [8192, 12288)
    h16* __restrict__ out)
{
    int bid = blockIdx.x;
    const float* src;
    size_t obase;
    int base;
    if (bid < 3072)      { src = a; obase = 0;       base = bid; }
    else if (bid < 4096) { src = b; obase = 3145728; base = bid - 3072; }
    else if (bid < 8192) { src = c; obase = 4194304; base = bid - 4096; }
    else                 { src = d; obase = 8388608; base = bid - 8192; }
    int i = base * 1024 + threadIdx.x * 4;
    float4 v = *(const float4*)(src + i);
    half4v o;
    o.x = (h16)v.x; o.y = (h16)v.y; o.z = (h16)v.z; o.w = (h16)v.w;
    *(half4v*)(out + obase + i) = o;
}

// ---------------------------------------------------------------------------
// LayerNorm: fp32 in, fp16 out. One block per row of E=1024.
// ---------------------------------------------------------------------------
__device__ inline float block_sum256(float v, float* sb) {
    #pragma unroll
    for (int o = 32; o > 0; o >>= 1) v += __shfl_down(v, o, 64);
    int lane = threadIdx.x & 63, w = threadIdx.x >> 6;
    if (lane == 0) sb[w] = v;
    __syncthreads();
    float r = sb[0] + sb[1] + sb[2] + sb[3];
    __syncthreads();
    return r;
}

__global__ __launch_bounds__(256) void ln_kernel(const float* __restrict__ x,
                                                 const float* __restrict__ g,
                                                 const float* __restrict__ b,
                                                 h16* __restrict__ out) {
    __shared__ float sb[4];
    int row = blockIdx.x;
    int t = threadIdx.x;
    const float* xr = x + (size_t)row * Ec;
    float4 v = ((const float4*)xr)[t];
    float s = v.x + v.y + v.z + v.w;
    float mu = block_sum256(s, sb) * (1.0f / Ec);
    float dx = v.x - mu, dy = v.y - mu, dz = v.z - mu, dw = v.w - mu;
    float ss = dx * dx + dy * dy + dz * dz + dw * dw;
    float var = block_sum256(ss, sb) * (1.0f / Ec);
    float inv = rsqrtf(var + 1e-5f);
    float4 gv = ((const float4*)g)[t];
    float4 bv = ((const float4*)b)[t];
    half4v o;
    o.x = (h16)(dx * inv * gv.x + bv.x);
    o.y = (h16)(dy * inv * gv.y + bv.y);
    o.z = (h16)(dz * inv * gv.z + bv.z);
    o.w = (h16)(dw * inv * gv.w + bv.w);
    ((half4v*)(out + (size_t)row * Ec))[t] = o;
}

// ---------------------------------------------------------------------------
// fp16 MFMA GEMM, 256x256 tile, 8 waves (512 thr, 2x4), BK=32, 4-deep LDS
// pipeline with counted vmcnt (T3+T4): stage tile t+3 while computing t,
// s_waitcnt vmcnt(8) + raw s_barrier per K-step (never drain to 0 in loop).
// LDS: 4 bufs x (A 256x32 + B 256x32) h16 = 128 KB. 1 block/CU.
// Wave tile 128x64 -> FLOP per LDS byte = 42.7 (balanced vs matrix pipe).
// Bank swizzle: logical (row, chunk) stored at physical chunk ^ ((row>>1)&3)
// -> ds_read_b128 frag reads are exactly 2-way (free). Swizzle applied on
// the pre-swizzled GLOBAL source addr (LDS dest stays linear, rule #21).
// lda = row stride of A and W (in h16); K = loop length (chunk).
// EPI: 0 = bias->h16, 2 = gelu(bias)->h16,
//      3 = SPLIT-K PO: grid 256 = 16 rowtiles x 4 coltiles x 4 splits.
//          splits 0-2 -> raw fp16 partial at (char*)R + {0, 8M, 24M};
//          split 3    -> raw f32 into C. No bias, no residual (red3 adds).
// Requires M,N %256==0, K%32==0, K>=96, gridDim %8==0 (XCD swizzle).
// ---------------------------------------------------------------------------
template <int EPI, typename OutT>
__global__ __launch_bounds__(512, 2) void gemm_8w(
    const h16* __restrict__ A, const h16* __restrict__ W,
    const float* __restrict__ bias, const float* __restrict__ R,
    OutT* __restrict__ C, int M, int N, int K, int lda)
{
    __shared__ h16 S[4][16384];   // [buf][ A: 0..8191 | B: 8192..16383 ] 128 KB

    const int tid = threadIdx.x;
    const int lane = tid & 63, wv = tid >> 6;
    const int wm = wv >> 2, wn = wv & 3;       // 2 x 4 wave grid
    const int c15 = lane & 15, q = lane >> 4;

    // XCD-aware bijective swizzle (gridDim.x % 8 == 0)
    const int cpx = gridDim.x >> 3;
    const int wg = ((int)blockIdx.x & 7) * cpx + ((int)blockIdx.x >> 3);
    int r0, c0, sp = 0;
    if (EPI == 3) {                 // 16 rowtiles x 4 coltiles x 4 K-splits
        sp = wg >> 6;
        int rem = wg & 63;
        r0 = (rem >> 2) << 8;
        c0 = (rem & 3) << 8;
    } else {
        const int nbn = N >> 8;
        r0 = (wg / nbn) << 8;
        c0 = (wg % nbn) << 8;
    }

    // staging map: thread -> (row = u*128 + tid>>2, one 16B chunk of 4).
    // Global chunk pre-swizzled so LDS slot (row, pc) holds logical pc^((row>>1)&3).
    const int gc8 = (tid & 3) ^ ((tid >> 3) & 3);
    const h16* gA = A + (size_t)(r0 + (tid >> 2)) * lda + sp * 1024 + gc8 * 8;
    const h16* gB = W + (size_t)(c0 + (tid >> 2)) * lda + sp * 1024 + gc8 * 8;
    const size_t hK = (size_t)128 * lda;       // u=1 row offset

    // ds_read offsets (h16 units), physical chunk = q ^ ((row>>1)&3)
    int aoff[8], boff[4];
    #pragma unroll
    for (int m = 0; m < 8; ++m) {
        int row = wm * 128 + m * 16 + c15;
        aoff[m] = row * 32 + ((q ^ ((row >> 1) & 3)) << 3);
    }
    #pragma unroll
    for (int n = 0; n < 4; ++n) {
        int row = wn * 64 + n * 16 + c15;
        boff[n] = 8192 + row * 32 + ((q ^ ((row >> 1) & 3)) << 3);
    }

    f32x4 acc[8][4];
    #pragma unroll
    for (int m = 0; m < 8; ++m)
        #pragma unroll
        for (int n = 0; n < 4; ++n)
            acc[m][n] = (f32x4){0.f, 0.f, 0.f, 0.f};

    const int NT = K >> 5;

    auto stage = [&](int tt) {                 // 4 gld_lds16 = one full tile
        h16* b = &S[tt & 3][0];
        const h16* a = gA + tt * 32;
        const h16* w = gB + tt * 32;
        gld_lds16(a,      b + tid * 8);
        gld_lds16(a + hK, b + 4096 + tid * 8);
        gld_lds16(w,      b + 8192 + tid * 8);
        gld_lds16(w + hK, b + 12288 + tid * 8);
    };

    // prologue: 3 tiles in flight; wait tile 0 (vmcnt 8 = tiles 1,2 outstanding)
    stage(0); stage(1); stage(2);
    asm volatile("s_waitcnt vmcnt(8)" ::: "memory");
    __builtin_amdgcn_s_barrier();

    for (int t = 0; t < NT; ++t) {
        if (t + 3 < NT) stage(t + 3);          // overwrites buf last read at t-1

        const h16* b = &S[t & 3][0];
        half8v af[8], bf[4];
        #pragma unroll
        for (int m = 0; m < 8; ++m) af[m] = *(const half8v*)(b + aoff[m]);
        #pragma unroll
        for (int n = 0; n < 4; ++n) bf[n] = *(const half8v*)(b + boff[n]);

        __builtin_amdgcn_s_setprio(1);
        #pragma unroll
        for (int m = 0; m < 8; ++m)
            #pragma unroll
            for (int n = 0; n < 4; ++n)
                acc[m][n] = __builtin_amdgcn_mfma_f32_16x16x32_f16(af[m], bf[n], acc[m][n], 0, 0, 0);
        __builtin_amdgcn_s_setprio(0);

        if (t < NT - 1) {                      // ensure tile t+1 landed, all waves
            if (t + 3 < NT)       asm volatile("s_waitcnt vmcnt(8)" ::: "memory");
            else if (t + 3 == NT) asm volatile("s_waitcnt vmcnt(4)" ::: "memory");
            else                  asm volatile("s_waitcnt vmcnt(0)" ::: "memory");
            __builtin_amdgcn_s_barrier();
        }
    }

    // epilogue: row = r0 + wm*128 + m*16 + q*4 + r, col = c0 + wn*64 + n*16 + c15
    h16* Pp = nullptr;
    if (EPI == 3 && sp < 3) {
        size_t po = (sp == 0) ? 0 : (sp == 1) ? 8388608u : 25165824u;
        Pp = (h16*)((char*)(void*)R + po);     // R = workspace base (partials)
    }
    float bvs[4];
    #pragma unroll
    for (int n = 0; n < 4; ++n) bvs[n] = bias[c0 + wn * 64 + n * 16 + c15];
    #pragma unroll
    for (int m = 0; m < 8; ++m) {
        #pragma unroll
        for (int n = 0; n < 4; ++n) {
            int col = c0 + wn * 64 + n * 16 + c15;
            #pragma unroll
            for (int r = 0; r < 4; ++r) {
                int row = r0 + wm * 128 + m * 16 + q * 4 + r;
                size_t off = (size_t)row * N + col;
                if (EPI == 3) {
                    float v = acc[m][n][r];    // raw partial (no bias/residual)
                    if (sp < 3) Pp[off] = (h16)v;
                    else ((float*)C)[off] = v;
                } else {
                    float v = acc[m][n][r] + bvs[n];
                    if (EPI == 1) v += R[off];
                    if (EPI == 2) v = gelu_new(v);
                    if (sizeof(OutT) == 2) ((h16*)C)[off] = (h16)v;
                    else ((float*)C)[off] = v;
                }
            }
        }
    }
}

// ---------------------------------------------------------------------------
// split-K reduce for PO: out = out(split3 raw) + x1 + bias + P0 + P1 + P2.
// 8 f32 elems/thread, grid 2048 x 256. N=1024 cols (8 | 1024, no row cross).
// ---------------------------------------------------------------------------
__global__ __launch_bounds__(256) void red3_kernel(
    const h16* __restrict__ P0, const h16* __restrict__ P1,
    const h16* __restrict__ P2, const float* __restrict__ xr,
    const float* __restrict__ bias, float* __restrict__ out)
{
    size_t i = ((size_t)blockIdx.x * 256 + threadIdx.x) * 8;
    int col = (int)(i & 1023);
    half8v p0 = *(const half8v*)(P0 + i);
    half8v p1 = *(const half8v*)(P1 + i);
    half8v p2 = *(const half8v*)(P2 + i);
    float4 x0 = *(const float4*)(xr + i);
    float4 x1v = *(const float4*)(xr + i + 4);
    float4 b0 = *(const float4*)(bias + col);
    float4 b1 = *(const float4*)(bias + col + 4);
    float4 o0 = *(const float4*)(out + i);
    float4 o1 = *(const float4*)(out + i + 4);
    float ps[8];
    #pragma unroll
    for (int u = 0; u < 8; ++u)
        ps[u] = (float)p0[u] + (float)p1[u] + (float)p2[u];
    o0.x += x0.x + b0.x + ps[0];
    o0.y += x0.y + b0.y + ps[1];
    o0.z += x0.z + b0.z + ps[2];
    o0.w += x0.w + b0.w + ps[3];
    o1.x += x1v.x + b1.x + ps[4];
    o1.y += x1v.y + b1.y + ps[5];
    o1.z += x1v.z + b1.z + ps[6];
    o1.w += x1v.w + b1.w + ps[7];
    *(float4*)(out + i) = o0;
    *(float4*)(out + i + 4) = o1;
}

// ---------------------------------------------------------------------------
// fp16 MFMA GEMM (skinny-N): BM=64, BN=128, BK=32, 4 waves (2x2), 4-deep LDS
// pipeline with counted vmcnt. Per step: 3 gld_lds16 || 6 ds_read_b128 ||
// 8 MFMA/wave; stage t+3 while computing t; vmcnt(6) per step, tail 3/0.
// LDS 4x12 KB = 48 KB -> 2 blocks/CU. 2-way bank swizzle (pre-swizzled
// global source, swizzled ds_read addr; LDS dest linear). XCD swizzle:
// grid 1D (512 = 8 cols x 64 rows). For AO (N=1024). K % 32 == 0, K >= 96.
// ---------------------------------------------------------------------------
template <int EPI, typename OutT>
__global__ __launch_bounds__(256, 2) void gemm_k64(
    const h16* __restrict__ A, const h16* __restrict__ W,
    const float* __restrict__ bias, const float* __restrict__ R,
    OutT* __restrict__ C, int M, int N, int K)
{
    __shared__ h16 S[4][6144];   // [buf][ A: 0..2047 | B: 2048..6143 ]  48 KB

    const int t = threadIdx.x;
    const int lane = t & 63, wv = t >> 6;
    const int wm = wv >> 1, wn = wv & 1;
    const int c15 = lane & 15, q = lane >> 4;
    // swizzle decode (grid 8x64 flattened): same id%8 => same row group on one XCD
    const int id = blockIdx.x;
    const int cx = id & 7;
    const int kq = id >> 3;
    const int bx = kq & 7;
    const int by = ((kq >> 3) << 3) | cx;
    const int row0 = by * 64, col0 = bx * 128;

    // staging: row = tid>>2 (+64 for B upper half), pre-swizzled global chunk
    const int gc8 = (t & 3) ^ ((t >> 3) & 3);
    const h16* gA  = A + (size_t)(row0 + (t >> 2)) * K + gc8 * 8;
    const h16* gB0 = W + (size_t)(col0 + (t >> 2)) * K + gc8 * 8;
    const h16* gB1 = gB0 + (size_t)64 * K;

    // ds_read offsets (h16 units), physical chunk = q ^ ((row>>1)&3)
    int aoff[2], boff[4];
    #pragma unroll
    for (int i = 0; i < 2; ++i) {
        int row = wm * 32 + i * 16 + c15;
        aoff[i] = row * 32 + ((q ^ ((row >> 1) & 3)) << 3);
    }
    #pragma unroll
    for (int j = 0; j < 4; ++j) {
        int row = wn * 64 + j * 16 + c15;
        boff[j] = 2048 + row * 32 + ((q ^ ((row >> 1) & 3)) << 3);
    }

    f32x4 acc[2][4];
    #pragma unroll
    for (int i = 0; i < 2; ++i)
        #pragma unroll
        for (int j = 0; j < 4; ++j)
            acc[i][j] = (f32x4){0.f, 0.f, 0.f, 0.f};

    const int NT = K >> 5;

    auto stage = [&](int tt) {                 // 3 gld_lds16 = one full tile
        h16* b = &S[tt & 3][0];
        gld_lds16(gA  + tt * 32, b + t * 8);
        gld_lds16(gB0 + tt * 32, b + 2048 + t * 8);
        gld_lds16(gB1 + tt * 32, b + 4096 + t * 8);
    };

    // prologue: 3 tiles in flight; wait tile 0 (vmcnt 6 = tiles 1,2 outstanding)
    stage(0); stage(1); stage(2);
    asm volatile("s_waitcnt vmcnt(6)" ::: "memory");
    __builtin_amdgcn_s_barrier();

    for (int tt = 0; tt < NT; ++tt) {
        if (tt + 3 < NT) stage(tt + 3);        // overwrites buf last read at tt-1

        const h16* b = &S[tt & 3][0];
        half8v af[2], bf[4];
        #pragma unroll
        for (int i = 0; i < 2; ++i) af[i] = *(const half8v*)(b + aoff[i]);
        #pragma unroll
        for (int j = 0; j < 4; ++j) bf[j] = *(const half8v*)(b + boff[j]);

        __builtin_amdgcn_s_setprio(1);
        #pragma unroll
        for (int i = 0; i < 2; ++i)
            #pragma unroll
            for (int j = 0; j < 4; ++j)
                acc[i][j] = __builtin_amdgcn_mfma_f32_16x16x32_f16(af[i], bf[j], acc[i][j], 0, 0, 0);
        __builtin_amdgcn_s_setprio(0);

        if (tt < NT - 1) {                     // ensure tile tt+1 landed, all waves
            if (tt + 3 < NT)       asm volatile("s_waitcnt vmcnt(6)" ::: "memory");
            else if (tt + 3 == NT) asm volatile("s_waitcnt vmcnt(3)" ::: "memory");
            else                   asm volatile("s_waitcnt vmcnt(0)" ::: "memory");
            __builtin_amdgcn_s_barrier();
        }
    }

    #pragma unroll
    for (int i = 0; i < 2; ++i) {
        #pragma unroll
        for (int j = 0; j < 4; ++j) {
            int col = col0 + wn * 64 + j * 16 + c15;
            float bv = bias[col];
            #pragma unroll
            for (int r = 0; r < 4; ++r) {
                int row = row0 + wm * 32 + i * 16 + q * 4 + r;
                size_t off = (size_t)row * N + col;
                float v = acc[i][j][r] + bv;
                if (EPI == 1) v += R[off];
                if (EPI == 2) v = gelu_new(v);
                if (sizeof(OutT) == 2) ((h16*)C)[off] = (h16)v;
                else ((float*)C)[off] = v;
            }
        }
    }
}

// ---------------------------------------------------------------------------
// Causal flash attention v3, fp16 MFMA, O^T formulation.
// Grid (32 bh, 16 pairs): block y runs q-tiles {31-y, y} sequentially ->
// every block does exactly 33 tile-steps (perfect load balance).
// S^T = K*Q^T and O^T = V^T*P^T -> col=query=c15: softmax state lane-local.
// K double-buffered via global_load_lds; V single-buffer reg-prefetch+scatter.
// Bank swizzle on Ks and Vt (physical chunk = logical ^ ((row>>1)&3)):
// Ks via pre-swizzled GLOBAL source (LDS dest linear, rule #21); Vt via
// swizzled scatter write. Reads use swz = q ^ ((c15>>1)&3) (row-bits from
// c15 only since tile rows are 16-aligned). Removes the 8-way quarter-wave
// conflict of 64B-stride rows (bank = 16*(row&1) for c15-varying lanes).
// ---------------------------------------------------------------------------
__global__ __launch_bounds__(256, 4) void attn_mfma(const h16* __restrict__ qkv,
                                                    h16* __restrict__ attn) {
    __shared__ h16 Ks[2][2][64 * 32];   // [buf][d-half][key*32+d]   16 KB
    __shared__ h16 Vt[2][64 * 32];      // [key-half][d*32+key]       8 KB
    __shared__ h16 Ps[4][16 * 72];      // [wave][query*72+key]       9 KB

    const int t = threadIdx.x;
    const int lane = t & 63, wv = t >> 6;
    const int c15 = lane & 15, q = lane >> 4;
    const int bh = blockIdx.x, b = bh >> 4, h = bh & 15;
    const int y = blockIdx.y;             // pair index 0..15
    const int SE = 3 * Ec;
    const size_t hbase = (size_t)b * Sc * SE + (size_t)h * (3 * HDc);

    const int krow = t >> 2;                          // K staging row
    const int kcol = (((t & 3) ^ ((t >> 3) & 3)) << 3);  // pre-swizzled global chunk
    const int vkey = t & 31, vd0 = (t >> 5) << 3;     // V staging
    half8v vreg[2];

    // swizzled ds_read chunk offset (h16): same for Ks and Vt reads
    const int ksw = (q ^ ((c15 >> 1) & 3)) << 3;
    // swizzled Vt scatter addresses (per-thread constant)
    int vaddr[8];
    #pragma unroll
    for (int u = 0; u < 8; ++u) {
        int d = vd0 + u;
        vaddr[u] = d * 32 + (((vkey >> 3) ^ ((d >> 1) & 3)) << 3) + (vkey & 7);
    }

    auto stageK = [&](int kt, int bf) {
        #pragma unroll
        for (int p = 0; p < 2; ++p)
            gld_lds16(qkv + hbase + (size_t)(kt * 64 + krow) * SE + HDc + p * 32 + kcol,
                      &Ks[bf][p][krow * 32 + ((t & 3) << 3)]);
    };
    auto loadV = [&](int kt) {
        #pragma unroll
        for (int p = 0; p < 2; ++p)
            vreg[p] = *(const half8v*)(qkv + hbase +
                        (size_t)(kt * 64 + p * 32 + vkey) * SE + 2 * HDc + vd0);
    };
    auto scatV = [&]() {
        #pragma unroll
        for (int p = 0; p < 2; ++p)
            #pragma unroll
            for (int u = 0; u < 8; ++u)
                Vt[p][vaddr[u]] = vreg[p][u];
    };

    #pragma unroll 1
    for (int seg = 0; seg < 2; ++seg) {
        const int ja = seg == 0 ? (31 - y) : y;
        const int qbase = ja * 64 + wv * 16;  // wave's 16 query rows

        // Q fragment, pre-scaled by 1/sqrt(64) = 0.125 (exact in fp16)
        half8v qf[2];
        #pragma unroll
        for (int kk = 0; kk < 2; ++kk) {
            qf[kk] = *(const half8v*)(qkv + hbase + (size_t)(qbase + c15) * SE + kk * 32 + q * 8);
            qf[kk] *= (h16)0.125f;
        }

        f32x4 O[4];   // O^T: [d-tile], col=query(c15), row=d-local(q*4+r)
        #pragma unroll
        for (int n = 0; n < 4; ++n) O[n] = (f32x4){0.f, 0.f, 0.f, 0.f};
        float mi = -3e38f, li = 0.f;

        if (seg == 1) __syncthreads();   // all waves done with seg0's Ks/Vt reads
        stageK(0, 0);
        loadV(0);
        scatV();
        __syncthreads();

        for (int kt = 0; kt <= ja; ++kt) {
            const int bf = kt & 1;
            if (kt < ja) { stageK(kt + 1, bf ^ 1); loadV(kt + 1); }

            // S^T = K*Q^T : st[j] rows=key-local(q*4+r), col=query(c15)
            f32x4 st[4];
            #pragma unroll
            for (int j = 0; j < 4; ++j) {
                half8v kf0 = *(const half8v*)&Ks[bf][0][(j * 16 + c15) * 32 + ksw];
                half8v kf1 = *(const half8v*)&Ks[bf][1][(j * 16 + c15) * 32 + ksw];
                f32x4 z = (f32x4){0.f, 0.f, 0.f, 0.f};
                z = __builtin_amdgcn_mfma_f32_16x16x32_f16(kf0, qf[0], z, 0, 0, 0);
                st[j] = __builtin_amdgcn_mfma_f32_16x16x32_f16(kf1, qf[1], z, 0, 0, 0);
            }

            // causal mask: only the diagonal tile needs it (wave-uniform branch)
            if (kt == ja) {
                const int rowloc = wv * 16 + c15;
                #pragma unroll
                for (int j = 0; j < 4; ++j)
                    #pragma unroll
                    for (int r = 0; r < 4; ++r)
                        if (j * 16 + q * 4 + r > rowloc) st[j][r] = -3e38f;
            }

            // online softmax; query owned by c15, its 64 keys spread over 4 q-groups
            float mx = mi;
            #pragma unroll
            for (int j = 0; j < 4; ++j)
                #pragma unroll
                for (int r = 0; r < 4; ++r) mx = fmaxf(mx, st[j][r]);
            mx = fmaxf(mx, __shfl_xor(mx, 16, 64));
            mx = fmaxf(mx, __shfl_xor(mx, 32, 64));
            float al = __expf(mi - mx);
            mi = mx;
            float ps = 0.f;
            #pragma unroll
            for (int j = 0; j < 4; ++j) {
                half4v pk;
                #pragma unroll
                for (int r = 0; r < 4; ++r) {
                    float p = __expf(st[j][r] - mx);
                    ps += p;
                    pk[r] = (h16)p;
                }
                *(half4v*)&Ps[wv][c15 * 72 + j * 16 + q * 4] = pk;
            }
            ps += __shfl_xor(ps, 16, 64);
            ps += __shfl_xor(ps, 32, 64);
            li = li * al + ps;

            // O^T += V^T * P^T ; alpha-rescale is lane-local (col=query=c15)
            half8v pb0 = *(const half8v*)&Ps[wv][c15 * 72 + q * 8];
            half8v pb1 = *(const half8v*)&Ps[wv][c15 * 72 + 32 + q * 8];
            #pragma unroll
            for (int n = 0; n < 4; ++n) {
                #pragma unroll
                for (int r = 0; r < 4; ++r) O[n][r] *= al;
                half8v va0 = *(const half8v*)&Vt[0][(n * 16 + c15) * 32 + ksw];
                half8v va1 = *(const half8v*)&Vt[1][(n * 16 + c15) * 32 + ksw];
                O[n] = __builtin_amdgcn_mfma_f32_16x16x32_f16(va0, pb0, O[n], 0, 0, 0);
                O[n] = __builtin_amdgcn_mfma_f32_16x16x32_f16(va1, pb1, O[n], 0, 0, 0);
            }

            if (kt < ja) {
                __syncthreads();   // all waves done reading Vt (and Ks[bf])
                scatV();           // write V(kt+1) into single Vt buffer
                __syncthreads();   // Vt + async Ks[bf^1] (vmcnt drain) ready
            }
        }

        // epilogue: query = qbase+c15, d = n*16 + q*4 + r (4 contiguous -> 8B store)
        float rl = 1.0f / li;
        #pragma unroll
        for (int n = 0; n < 4; ++n) {
            half4v o4;
            #pragma unroll
            for (int r = 0; r < 4; ++r) o4[r] = (h16)(O[n][r] * rl);
            *(half4v*)(attn + ((size_t)(b * Sc + qbase + c15)) * Ec + h * HDc + n * 16 + q * 4) = o4;
        }
    }
}

// ---------------------------------------------------------------------------
extern "C" void kernel_launch(void* const* d_in, const int* in_sizes, int n_in,
                              void* d_out, int out_size, void* d_ws, size_t ws_size,
                              hipStream_t stream) {
    const float* x     = (const float*)d_in[0];
    const float* ln1_g = (const float*)d_in[1];
    const float* ln1_b = (const float*)d_in[2];
    const float* ln2_g = (const float*)d_in[3];
    const float* ln2_b = (const float*)d_in[4];
    const float* w_qkv = (const float*)d_in[5];
    const float* b_qkv = (const float*)d_in[6];
    const float* w_ao  = (const float*)d_in[7];
    const float* b_ao  = (const float*)d_in[8];
    const float* w_fc  = (const float*)d_in[9];
    const float* b_fc  = (const float*)d_in[10];
    const float* w_po  = (const float*)d_in[11];
    const float* b_po  = (const float*)d_in[12];
    float* out = (float*)d_out;

    // workspace (80 MB total):
    char* w = (char*)d_ws;
    h16* wqkv = (h16*)(w);             // 6 MB   (cvt4 outputs contiguous)
    h16* wao  = (h16*)(w + 6291456);   // 2 MB
    h16* wfc  = (h16*)(w + 8388608);   // 8 MB
    h16* wpo  = (h16*)(w + 16777216);  // 8 MB
    h16* hb   = (h16*)(w + 25165824);  // 8 MB  (fp16 LN out, reused)
    h16* qkv  = (h16*)(w + 33554432);  // 24 MB
    h16* attn = (h16*)(w + 58720256);  // 8 MB
    float* x1 = (float*)(w + 67108864);// 16 MB
    h16* ff   = qkv;                   // 32 MB alias over qkv+attn (dead)
    // PO split-K partials (all dead at PO time):
    //   P0 = w + 0        (wqkv+wao region, 8 MB)
    //   P1 = w + 8388608  (wfc region, 8 MB)
    //   P2 = w + 25165824 (hb region, 8 MB)

    dim3 blk(256);
    dim3 blk8(512);

    // fused weight converts fp32 -> fp16 (one launch)
    cvt4_kernel<<<dim3(12288), blk, 0, stream>>>(w_qkv, w_ao, w_fc, w_po, wqkv);

    // 1. hb = LN1(x)
    ln_kernel<<<dim3(ROWS), blk, 0, stream>>>(x, ln1_g, ln1_b, hb);
    // 2. qkv = hb @ w_qkv^T + b_qkv   (fp16 out)  [256^2 8-wave deep pipeline]
    gemm_8w<0, h16><<<dim3((ROWS / 256) * (3 * Ec / 256)), blk8, 0, stream>>>(
        hb, wqkv, b_qkv, nullptr, qkv, ROWS, 3 * Ec, Ec, Ec);
    // 3. attn = causal_flash_attention(qkv)   (fp16 out)  [paired q-tiles]
    attn_mfma<<<dim3(Bc * Hc, 16), blk, 0, stream>>>(qkv, attn);
    // 4. x1 = x + attn @ w_ao^T + b_ao  (fp32)   [1D grid, XCD swizzle, 4-deep]
    gemm_k64<1, float><<<dim3(512), blk, 0, stream>>>(
        attn, wao, b_ao, x, x1, ROWS, Ec, Ec);
    // 5. hb = LN2(x1)
    ln_kernel<<<dim3(ROWS), blk, 0, stream>>>(x1, ln2_g, ln2_b, hb);
    // 6. ff = gelu(hb @ w_fc^T + b_fc)  (fp16)   [256^2 8-wave deep pipeline]
    gemm_8w<2, h16><<<dim3((ROWS / 256) * (DFFc / 256)), blk8, 0, stream>>>(
        hb, wfc, b_fc, nullptr, ff, ROWS, DFFc, Ec, Ec);
    // 7a. PO split-K=4: splits 0-2 -> fp16 partials in ws, split 3 -> f32 out
    gemm_8w<3, float><<<dim3(256), blk8, 0, stream>>>(
        ff, wpo, b_po, (const float*)w, out, ROWS, Ec, 1024, DFFc);
    // 7b. out = out + x1 + b_po + P0 + P1 + P2
    red3_kernel<<<dim3(2048), blk, 0, stream>>>(
        (const h16*)w, (const h16*)(w + 8388608), (const h16*)(w + 25165824),
        x1, b_po, out);
}

// Round 6
// 322.398 us; speedup vs baseline: 1.0508x; 1.0508x over previous
//
#include <hip/hip_runtime.h>
#include <cstddef>
#include <cstdint>

#define Bc 2
#define Sc 2048
#define Ec 1024
#define Hc 16
#define HDc 64
#define DFFc 4096
#define ROWS (Bc * Sc)  // 4096

typedef _Float16 half8v __attribute__((ext_vector_type(8)));  // 8 fp16 (4 VGPR)
typedef _Float16 half4v __attribute__((ext_vector_type(4)));
typedef float f32x4 __attribute__((ext_vector_type(4)));      // MFMA C/D frag
typedef _Float16 h16;

// async global->LDS, 16B per lane. LDS dest must be wave-uniform base + lane*16.
__device__ inline void gld_lds16(const void* g, void* l) {
    __builtin_amdgcn_global_load_lds(
        (const __attribute__((address_space(1))) void*)g,
        (__attribute__((address_space(3))) void*)l, 16, 0, 0);
}

// gelu_new via sigmoid identity: 0.5x(1+tanh(z)) == x*sigmoid(2z).
__device__ inline float gelu_new(float x) {
    float x2 = x * x;
    float u = x * fmaf(0.07135481627362f, x2, 1.5957691216057308f);
    return x / (1.0f + __expf(-u));
}

// ---------------------------------------------------------------------------
// fused fp32 -> fp16 convert for all 4 weights (outputs contiguous in ws)
// ---------------------------------------------------------------------------
__global__ __launch_bounds__(256) void cvt4_kernel(
    const float* __restrict__ a,  // 3M elems  -> blocks [0, 3072)
    const float* __restrict__ b,  // 1M elems  -> blocks [3072, 4096)
    const float* __restrict__ c,  // 4M elems  -> blocks [4096, 8192)
    const float* __restrict__ d,  // 4M elems  -> blocks [8192, 12288)
    h16* __restrict__ out)
{
    int bid = blockIdx.x;
    const float* src;
    size_t obase;
    int base;
    if (bid < 3072)      { src = a; obase = 0;       base = bid; }
    else if (bid < 4096) { src = b; obase = 3145728; base = bid - 3072; }
    else if (bid < 8192) { src = c; obase = 4194304; base = bid - 4096; }
    else                 { src = d; obase = 8388608; base = bid - 8192; }
    int i = base * 1024 + threadIdx.x * 4;
    float4 v = *(const float4*)(src + i);
    half4v o;
    o.x = (h16)v.x; o.y = (h16)v.y; o.z = (h16)v.z; o.w = (h16)v.w;
    *(half4v*)(out + obase + i) = o;
}

// ---------------------------------------------------------------------------
// LayerNorm: fp32 in, fp16 out. One block per row of E=1024.
// ---------------------------------------------------------------------------
__device__ inline float block_sum256(float v, float* sb) {
    #pragma unroll
    for (int o = 32; o > 0; o >>= 1) v += __shfl_down(v, o, 64);
    int lane = threadIdx.x & 63, w = threadIdx.x >> 6;
    if (lane == 0) sb[w] = v;
    __syncthreads();
    float r = sb[0] + sb[1] + sb[2] + sb[3];
    __syncthreads();
    return r;
}

__global__ __launch_bounds__(256) void ln_kernel(const float* __restrict__ x,
                                                 const float* __restrict__ g,
                                                 const float* __restrict__ b,
                                                 h16* __restrict__ out) {
    __shared__ float sb[4];
    int row = blockIdx.x;
    int t = threadIdx.x;
    const float* xr = x + (size_t)row * Ec;
    float4 v = ((const float4*)xr)[t];
    float s = v.x + v.y + v.z + v.w;
    float mu = block_sum256(s, sb) * (1.0f / Ec);
    float dx = v.x - mu, dy = v.y - mu, dz = v.z - mu, dw = v.w - mu;
    float ss = dx * dx + dy * dy + dz * dz + dw * dw;
    float var = block_sum256(ss, sb) * (1.0f / Ec);
    float inv = rsqrtf(var + 1e-5f);
    float4 gv = ((const float4*)g)[t];
    float4 bv = ((const float4*)b)[t];
    half4v o;
    o.x = (h16)(dx * inv * gv.x + bv.x);
    o.y = (h16)(dy * inv * gv.y + bv.y);
    o.z = (h16)(dz * inv * gv.z + bv.z);
    o.w = (h16)(dw * inv * gv.w + bv.w);
    ((half4v*)(out + (size_t)row * Ec))[t] = o;
}

// ---------------------------------------------------------------------------
// fp16 MFMA GEMM, 256x256 tile, 8 waves (512 thr, 2x4), BK=32, 4-deep LDS
// prefetch with counted vmcnt + ONE-TILE-AHEAD fragment read pipeline:
// per step: stage(t+3); vmcnt(8); lgkmcnt(0); barrier;
//           read af_hi(t); MFMA half1 on (aflo(t), bf(t)) read LAST step;
//           read aflo(t+1)+bf(t+1); MFMA half2 on (af_hi(t), bf(t)).
// MFMA never waits on this step's LDS drain -> LDS pipe overlaps matrix pipe.
// lgkmcnt(0) before each barrier closes the cross-wave read-vs-overwrite
// LDS race (reads of buf b complete before any wave stages into b).
// LDS: 4 bufs x (A 256x32 + B 256x32) h16 = 128 KB. 1 block/CU.
// Bank swizzle: logical (row, chunk) stored at physical chunk ^ ((row>>1)&3)
// (pre-swizzled GLOBAL source; LDS dest linear, rule #21) -> 2-way reads.
// lda = row stride of A and W (in h16); K = loop length (chunk).
// EPI: 0 = bias->h16, 2 = gelu(bias)->h16,
//      3 = SPLIT-K PO: grid 256 = 16 rowtiles x 4 coltiles x 4 splits.
//          splits 0-2 -> raw fp16 partial at (char*)R + {0, 8M, 24M};
//          split 3    -> raw f32 into C. No bias, no residual (red3 adds).
// Requires M,N %256==0, K%64==0 (NT even), K>=128, gridDim %8==0.
// ---------------------------------------------------------------------------
template <int EPI, typename OutT>
__global__ __launch_bounds__(512, 2) void gemm_8w(
    const h16* __restrict__ A, const h16* __restrict__ W,
    const float* __restrict__ bias, const float* __restrict__ R,
    OutT* __restrict__ C, int M, int N, int K, int lda)
{
    __shared__ h16 S[4][16384];   // [buf][ A: 0..8191 | B: 8192..16383 ] 128 KB

    const int tid = threadIdx.x;
    const int lane = tid & 63, wv = tid >> 6;
    const int wm = wv >> 2, wn = wv & 3;       // 2 x 4 wave grid
    const int c15 = lane & 15, q = lane >> 4;

    // XCD-aware bijective swizzle (gridDim.x % 8 == 0)
    const int cpx = gridDim.x >> 3;
    const int wg = ((int)blockIdx.x & 7) * cpx + ((int)blockIdx.x >> 3);
    int r0, c0, sp = 0;
    if (EPI == 3) {                 // 16 rowtiles x 4 coltiles x 4 K-splits
        sp = wg >> 6;
        int rem = wg & 63;
        r0 = (rem >> 2) << 8;
        c0 = (rem & 3) << 8;
    } else {
        const int nbn = N >> 8;
        r0 = (wg / nbn) << 8;
        c0 = (wg % nbn) << 8;
    }

    // staging map: thread -> (row = u*128 + tid>>2, one 16B chunk of 4).
    // Global chunk pre-swizzled so LDS slot (row, pc) holds logical pc^((row>>1)&3).
    const int gc8 = (tid & 3) ^ ((tid >> 3) & 3);
    const h16* gA = A + (size_t)(r0 + (tid >> 2)) * lda + sp * 1024 + gc8 * 8;
    const h16* gB = W + (size_t)(c0 + (tid >> 2)) * lda + sp * 1024 + gc8 * 8;
    const size_t hK = (size_t)128 * lda;       // u=1 row offset

    // ds_read offsets (h16 units), physical chunk = q ^ ((row>>1)&3)
    int aoff[8], boff[4];
    #pragma unroll
    for (int m = 0; m < 8; ++m) {
        int row = wm * 128 + m * 16 + c15;
        aoff[m] = row * 32 + ((q ^ ((row >> 1) & 3)) << 3);
    }
    #pragma unroll
    for (int n = 0; n < 4; ++n) {
        int row = wn * 64 + n * 16 + c15;
        boff[n] = 8192 + row * 32 + ((q ^ ((row >> 1) & 3)) << 3);
    }

    f32x4 acc[8][4];
    #pragma unroll
    for (int m = 0; m < 8; ++m)
        #pragma unroll
        for (int n = 0; n < 4; ++n)
            acc[m][n] = (f32x4){0.f, 0.f, 0.f, 0.f};

    const int NT = K >> 5;   // even, >= 4 at all call sites

    auto stage = [&](int tt) {                 // 4 gld_lds16 = one full tile
        h16* b = &S[tt & 3][0];
        const h16* a = gA + tt * 32;
        const h16* w = gB + tt * 32;
        gld_lds16(a,      b + tid * 8);
        gld_lds16(a + hK, b + 4096 + tid * 8);
        gld_lds16(w,      b + 8192 + tid * 8);
        gld_lds16(w + 12288 - 8192 + hK - hK, b + 12288 + tid * 8); // placeholder, replaced below
    };
    (void)stage;
    auto stage4 = [&](int tt) {
        h16* b = &S[tt & 3][0];
        const h16* a = gA + tt * 32;
        const h16* w = gB + tt * 32;
        gld_lds16(a,      b + tid * 8);
        gld_lds16(a + hK, b + 4096 + tid * 8);
        gld_lds16(w,      b + 8192 + tid * 8);
        gld_lds16(w + hK, b + 12288 + tid * 8);
    };

    half8v afloA[4], bfA[4], afloB[4], bfB[4];

    // one pipeline step: consumes (aflo, bf) = tile s operands (read at step
    // s-1); reads af_hi(s) early and (aflo2, bf2) = tile s+1 mid-step.
    auto step = [&](int s, half8v (&aflo)[4], half8v (&bf)[4],
                    half8v (&aflo2)[4], half8v (&bf2)[4]) {
        if (s + 3 < NT) stage4(s + 3);
        if (s + 3 < NT)      asm volatile("s_waitcnt vmcnt(8)" ::: "memory");
        else if (s + 2 < NT) asm volatile("s_waitcnt vmcnt(4)" ::: "memory");
        else if (s + 1 < NT) asm volatile("s_waitcnt vmcnt(0)" ::: "memory");
        if (s + 1 < NT) {
            // all of this wave's prior-step ds_reads complete before any wave
            // can overwrite their source buffer after the barrier
            asm volatile("s_waitcnt lgkmcnt(0)" ::: "memory");
            __builtin_amdgcn_s_barrier();
        }
        const h16* b = &S[s & 3][0];
        half8v ah[4];                          // af_hi(s): m = 4..7
        #pragma unroll
        for (int m = 0; m < 4; ++m) ah[m] = *(const half8v*)(b + aoff[4 + m]);

        __builtin_amdgcn_s_setprio(1);
        #pragma unroll
        for (int m = 0; m < 4; ++m)
            #pragma unroll
            for (int n = 0; n < 4; ++n)
                acc[m][n] = __builtin_amdgcn_mfma_f32_16x16x32_f16(aflo[m], bf[n], acc[m][n], 0, 0, 0);
        __builtin_amdgcn_s_setprio(0);

        if (s + 1 < NT) {                      // read tile s+1 under the MFMAs
            const h16* b2 = &S[(s + 1) & 3][0];
            #pragma unroll
            for (int m = 0; m < 4; ++m) aflo2[m] = *(const half8v*)(b2 + aoff[m]);
            #pragma unroll
            for (int n = 0; n < 4; ++n) bf2[n]  = *(const half8v*)(b2 + boff[n]);
        }

        __builtin_amdgcn_s_setprio(1);
        #pragma unroll
        for (int m = 0; m < 4; ++m)
            #pragma unroll
            for (int n = 0; n < 4; ++n)
                acc[4 + m][n] = __builtin_amdgcn_mfma_f32_16x16x32_f16(ah[m], bf[n], acc[4 + m][n], 0, 0, 0);
        __builtin_amdgcn_s_setprio(0);
    };

    // prologue: 3 tiles in flight; wait tile 0; read tile 0 lo-frags
    stage4(0); stage4(1); stage4(2);
    asm volatile("s_waitcnt vmcnt(8)" ::: "memory");
    __builtin_amdgcn_s_barrier();
    {
        const h16* b0 = &S[0][0];
        #pragma unroll
        for (int m = 0; m < 4; ++m) afloA[m] = *(const half8v*)(b0 + aoff[m]);
        #pragma unroll
        for (int n = 0; n < 4; ++n) bfA[n] = *(const half8v*)(b0 + boff[n]);
    }

    for (int t = 0; t < NT; t += 2) {
        step(t,     afloA, bfA, afloB, bfB);
        step(t + 1, afloB, bfB, afloA, bfA);
    }

    // epilogue: row = r0 + wm*128 + m*16 + q*4 + r, col = c0 + wn*64 + n*16 + c15
    h16* Pp = nullptr;
    if (EPI == 3 && sp < 3) {
        size_t po = (sp == 0) ? 0 : (sp == 1) ? 8388608u : 25165824u;
        Pp = (h16*)((char*)(void*)R + po);     // R = workspace base (partials)
    }
    float bvs[4];
    #pragma unroll
    for (int n = 0; n < 4; ++n) bvs[n] = bias[c0 + wn * 64 + n * 16 + c15];
    #pragma unroll
    for (int m = 0; m < 8; ++m) {
        #pragma unroll
        for (int n = 0; n < 4; ++n) {
            int col = c0 + wn * 64 + n * 16 + c15;
            #pragma unroll
            for (int r = 0; r < 4; ++r) {
                int row = r0 + wm * 128 + m * 16 + q * 4 + r;
                size_t off = (size_t)row * N + col;
                if (EPI == 3) {
                    float v = acc[m][n][r];    // raw partial (no bias/residual)
                    if (sp < 3) Pp[off] = (h16)v;
                    else ((float*)C)[off] = v;
                } else {
                    float v = acc[m][n][r] + bvs[n];
                    if (EPI == 1) v += R[off];
                    if (EPI == 2) v = gelu_new(v);
                    if (sizeof(OutT) == 2) ((h16*)C)[off] = (h16)v;
                    else ((float*)C)[off] = v;
                }
            }
        }
    }
}

// ---------------------------------------------------------------------------
// split-K reduce for PO: out = out(split3 raw) + x1 + bias + P0 + P1 + P2.
// 8 f32 elems/thread, grid 2048 x 256. N=1024 cols (8 | 1024, no row cross).
// ---------------------------------------------------------------------------
__global__ __launch_bounds__(256) void red3_kernel(
    const h16* __restrict__ P0, const h16* __restrict__ P1,
    const h16* __restrict__ P2, const float* __restrict__ xr,
    const float* __restrict__ bias, float* __restrict__ out)
{
    size_t i = ((size_t)blockIdx.x * 256 + threadIdx.x) * 8;
    int col = (int)(i & 1023);
    half8v p0 = *(const half8v*)(P0 + i);
    half8v p1 = *(const half8v*)(P1 + i);
    half8v p2 = *(const half8v*)(P2 + i);
    float4 x0 = *(const float4*)(xr + i);
    float4 x1v = *(const float4*)(xr + i + 4);
    float4 b0 = *(const float4*)(bias + col);
    float4 b1 = *(const float4*)(bias + col + 4);
    float4 o0 = *(const float4*)(out + i);
    float4 o1 = *(const float4*)(out + i + 4);
    float ps[8];
    #pragma unroll
    for (int u = 0; u < 8; ++u)
        ps[u] = (float)p0[u] + (float)p1[u] + (float)p2[u];
    o0.x += x0.x + b0.x + ps[0];
    o0.y += x0.y + b0.y + ps[1];
    o0.z += x0.z + b0.z + ps[2];
    o0.w += x0.w + b0.w + ps[3];
    o1.x += x1v.x + b1.x + ps[4];
    o1.y += x1v.y + b1.y + ps[5];
    o1.z += x1v.z + b1.z + ps[6];
    o1.w += x1v.w + b1.w + ps[7];
    *(float4*)(out + i) = o0;
    *(float4*)(out + i + 4) = o1;
}

// ---------------------------------------------------------------------------
// fp16 MFMA GEMM (skinny-N): BM=64, BN=128, BK=32, 4 waves (2x2), 4-deep LDS
// pipeline with counted vmcnt. Per step: 3 gld_lds16 || 6 ds_read_b128 ||
// 8 MFMA/wave; stage t+3 while computing t; vmcnt(6) per step, tail 3/0.
// LDS 4x12 KB = 48 KB -> 2 blocks/CU. 2-way bank swizzle (pre-swizzled
// global source, swizzled ds_read addr; LDS dest linear). XCD swizzle:
// grid 1D (512 = 8 cols x 64 rows). For AO (N=1024). K % 32 == 0, K >= 96.
// ---------------------------------------------------------------------------
template <int EPI, typename OutT>
__global__ __launch_bounds__(256, 2) void gemm_k64(
    const h16* __restrict__ A, const h16* __restrict__ W,
    const float* __restrict__ bias, const float* __restrict__ R,
    OutT* __restrict__ C, int M, int N, int K)
{
    __shared__ h16 S[4][6144];   // [buf][ A: 0..2047 | B: 2048..6143 ]  48 KB

    const int t = threadIdx.x;
    const int lane = t & 63, wv = t >> 6;
    const int wm = wv >> 1, wn = wv & 1;
    const int c15 = lane & 15, q = lane >> 4;
    // swizzle decode (grid 8x64 flattened): same id%8 => same row group on one XCD
    const int id = blockIdx.x;
    const int cx = id & 7;
    const int kq = id >> 3;
    const int bx = kq & 7;
    const int by = ((kq >> 3) << 3) | cx;
    const int row0 = by * 64, col0 = bx * 128;

    // staging: row = tid>>2 (+64 for B upper half), pre-swizzled global chunk
    const int gc8 = (t & 3) ^ ((t >> 3) & 3);
    const h16* gA  = A + (size_t)(row0 + (t >> 2)) * K + gc8 * 8;
    const h16* gB0 = W + (size_t)(col0 + (t >> 2)) * K + gc8 * 8;
    const h16* gB1 = gB0 + (size_t)64 * K;

    // ds_read offsets (h16 units), physical chunk = q ^ ((row>>1)&3)
    int aoff[2], boff[4];
    #pragma unroll
    for (int i = 0; i < 2; ++i) {
        int row = wm * 32 + i * 16 + c15;
        aoff[i] = row * 32 + ((q ^ ((row >> 1) & 3)) << 3);
    }
    #pragma unroll
    for (int j = 0; j < 4; ++j) {
        int row = wn * 64 + j * 16 + c15;
        boff[j] = 2048 + row * 32 + ((q ^ ((row >> 1) & 3)) << 3);
    }

    f32x4 acc[2][4];
    #pragma unroll
    for (int i = 0; i < 2; ++i)
        #pragma unroll
        for (int j = 0; j < 4; ++j)
            acc[i][j] = (f32x4){0.f, 0.f, 0.f, 0.f};

    const int NT = K >> 5;

    auto stage = [&](int tt) {                 // 3 gld_lds16 = one full tile
        h16* b = &S[tt & 3][0];
        gld_lds16(gA  + tt * 32, b + t * 8);
        gld_lds16(gB0 + tt * 32, b + 2048 + t * 8);
        gld_lds16(gB1 + tt * 32, b + 4096 + t * 8);
    };

    // prologue: 3 tiles in flight; wait tile 0 (vmcnt 6 = tiles 1,2 outstanding)
    stage(0); stage(1); stage(2);
    asm volatile("s_waitcnt vmcnt(6)" ::: "memory");
    __builtin_amdgcn_s_barrier();

    for (int tt = 0; tt < NT; ++tt) {
        if (tt + 3 < NT) stage(tt + 3);        // overwrites buf last read at tt-1

        const h16* b = &S[tt & 3][0];
        half8v af[2], bf[4];
        #pragma unroll
        for (int i = 0; i < 2; ++i) af[i] = *(const half8v*)(b + aoff[i]);
        #pragma unroll
        for (int j = 0; j < 4; ++j) bf[j] = *(const half8v*)(b + boff[j]);

        __builtin_amdgcn_s_setprio(1);
        #pragma unroll
        for (int i = 0; i < 2; ++i)
            #pragma unroll
            for (int j = 0; j < 4; ++j)
                acc[i][j] = __builtin_amdgcn_mfma_f32_16x16x32_f16(af[i], bf[j], acc[i][j], 0, 0, 0);
        __builtin_amdgcn_s_setprio(0);

        if (tt < NT - 1) {                     // ensure tile tt+1 landed, all waves
            if (tt + 3 < NT)       asm volatile("s_waitcnt vmcnt(6)" ::: "memory");
            else if (tt + 3 == NT) asm volatile("s_waitcnt vmcnt(3)" ::: "memory");
            else                   asm volatile("s_waitcnt vmcnt(0)" ::: "memory");
            __builtin_amdgcn_s_barrier();
        }
    }

    #pragma unroll
    for (int i = 0; i < 2; ++i) {
        #pragma unroll
        for (int j = 0; j < 4; ++j) {
            int col = col0 + wn * 64 + j * 16 + c15;
            float bv = bias[col];
            #pragma unroll
            for (int r = 0; r < 4; ++r) {
                int row = row0 + wm * 32 + i * 16 + q * 4 + r;
                size_t off = (size_t)row * N + col;
                float v = acc[i][j][r] + bv;
                if (EPI == 1) v += R[off];
                if (EPI == 2) v = gelu_new(v);
                if (sizeof(OutT) == 2) ((h16*)C)[off] = (h16)v;
                else ((float*)C)[off] = v;
            }
        }
    }
}

// ---------------------------------------------------------------------------
// Causal flash attention v3, fp16 MFMA, O^T formulation.
// Grid (32 bh, 16 pairs): block y runs q-tiles {31-y, y} sequentially ->
// every block does exactly 33 tile-steps (perfect load balance).
// S^T = K*Q^T and O^T = V^T*P^T -> col=query=c15: softmax state lane-local.
// K double-buffered via global_load_lds; V single-buffer reg-prefetch+scatter.
// Bank swizzle on Ks and Vt (physical chunk = logical ^ ((row>>1)&3)):
// Ks via pre-swizzled GLOBAL source (LDS dest linear, rule #21); Vt via
// swizzled scatter write. Reads use swz = q ^ ((c15>>1)&3).
// ---------------------------------------------------------------------------
__global__ __launch_bounds__(256, 4) void attn_mfma(const h16* __restrict__ qkv,
                                                    h16* __restrict__ attn) {
    __shared__ h16 Ks[2][2][64 * 32];   // [buf][d-half][key*32+d]   16 KB
    __shared__ h16 Vt[2][64 * 32];      // [key-half][d*32+key]       8 KB
    __shared__ h16 Ps[4][16 * 72];      // [wave][query*72+key]       9 KB

    const int t = threadIdx.x;
    const int lane = t & 63, wv = t >> 6;
    const int c15 = lane & 15, q = lane >> 4;
    const int bh = blockIdx.x, b = bh >> 4, h = bh & 15;
    const int y = blockIdx.y;             // pair index 0..15
    const int SE = 3 * Ec;
    const size_t hbase = (size_t)b * Sc * SE + (size_t)h * (3 * HDc);

    const int krow = t >> 2;                          // K staging row
    const int kcol = (((t & 3) ^ ((t >> 3) & 3)) << 3);  // pre-swizzled global chunk
    const int vkey = t & 31, vd0 = (t >> 5) << 3;     // V staging
    half8v vreg[2];

    // swizzled ds_read chunk offset (h16): same for Ks and Vt reads
    const int ksw = (q ^ ((c15 >> 1) & 3)) << 3;
    // swizzled Vt scatter addresses (per-thread constant)
    int vaddr[8];
    #pragma unroll
    for (int u = 0; u < 8; ++u) {
        int d = vd0 + u;
        vaddr[u] = d * 32 + (((vkey >> 3) ^ ((d >> 1) & 3)) << 3) + (vkey & 7);
    }

    auto stageK = [&](int kt, int bf) {
        #pragma unroll
        for (int p = 0; p < 2; ++p)
            gld_lds16(qkv + hbase + (size_t)(kt * 64 + krow) * SE + HDc + p * 32 + kcol,
                      &Ks[bf][p][krow * 32 + ((t & 3) << 3)]);
    };
    auto loadV = [&](int kt) {
        #pragma unroll
        for (int p = 0; p < 2; ++p)
            vreg[p] = *(const half8v*)(qkv + hbase +
                        (size_t)(kt * 64 + p * 32 + vkey) * SE + 2 * HDc + vd0);
    };
    auto scatV = [&]() {
        #pragma unroll
        for (int p = 0; p < 2; ++p)
            #pragma unroll
            for (int u = 0; u < 8; ++u)
                Vt[p][vaddr[u]] = vreg[p][u];
    };

    #pragma unroll 1
    for (int seg = 0; seg < 2; ++seg) {
        const int ja = seg == 0 ? (31 - y) : y;
        const int qbase = ja * 64 + wv * 16;  // wave's 16 query rows

        // Q fragment, pre-scaled by 1/sqrt(64) = 0.125 (exact in fp16)
        half8v qf[2];
        #pragma unroll
        for (int kk = 0; kk < 2; ++kk) {
            qf[kk] = *(const half8v*)(qkv + hbase + (size_t)(qbase + c15) * SE + kk * 32 + q * 8);
            qf[kk] *= (h16)0.125f;
        }

        f32x4 O[4];   // O^T: [d-tile], col=query(c15), row=d-local(q*4+r)
        #pragma unroll
        for (int n = 0; n < 4; ++n) O[n] = (f32x4){0.f, 0.f, 0.f, 0.f};
        float mi = -3e38f, li = 0.f;

        if (seg == 1) __syncthreads();   // all waves done with seg0's Ks/Vt reads
        stageK(0, 0);
        loadV(0);
        scatV();
        __syncthreads();

        for (int kt = 0; kt <= ja; ++kt) {
            const int bf = kt & 1;
            if (kt < ja) { stageK(kt + 1, bf ^ 1); loadV(kt + 1); }

            // S^T = K*Q^T : st[j] rows=key-local(q*4+r), col=query(c15)
            f32x4 st[4];
            #pragma unroll
            for (int j = 0; j < 4; ++j) {
                half8v kf0 = *(const half8v*)&Ks[bf][0][(j * 16 + c15) * 32 + ksw];
                half8v kf1 = *(const half8v*)&Ks[bf][1][(j * 16 + c15) * 32 + ksw];
                f32x4 z = (f32x4){0.f, 0.f, 0.f, 0.f};
                z = __builtin_amdgcn_mfma_f32_16x16x32_f16(kf0, qf[0], z, 0, 0, 0);
                st[j] = __builtin_amdgcn_mfma_f32_16x16x32_f16(kf1, qf[1], z, 0, 0, 0);
            }

            // causal mask: only the diagonal tile needs it (wave-uniform branch)
            if (kt == ja) {
                const int rowloc = wv * 16 + c15;
                #pragma unroll
                for (int j = 0; j < 4; ++j)
                    #pragma unroll
                    for (int r = 0; r < 4; ++r)
                        if (j * 16 + q * 4 + r > rowloc) st[j][r] = -3e38f;
            }

            // online softmax; query owned by c15, its 64 keys spread over 4 q-groups
            float mx = mi;
            #pragma unroll
            for (int j = 0; j < 4; ++j)
                #pragma unroll
                for (int r = 0; r < 4; ++r) mx = fmaxf(mx, st[j][r]);
            mx = fmaxf(mx, __shfl_xor(mx, 16, 64));
            mx = fmaxf(mx, __shfl_xor(mx, 32, 64));
            float al = __expf(mi - mx);
            mi = mx;
            float ps = 0.f;
            #pragma unroll
            for (int j = 0; j < 4; ++j) {
                half4v pk;
                #pragma unroll
                for (int r = 0; r < 4; ++r) {
                    float p = __expf(st[j][r] - mx);
                    ps += p;
                    pk[r] = (h16)p;
                }
                *(half4v*)&Ps[wv][c15 * 72 + j * 16 + q * 4] = pk;
            }
            ps += __shfl_xor(ps, 16, 64);
            ps += __shfl_xor(ps, 32, 64);
            li = li * al + ps;

            // O^T += V^T * P^T ; alpha-rescale is lane-local (col=query=c15)
            half8v pb0 = *(const half8v*)&Ps[wv][c15 * 72 + q * 8];
            half8v pb1 = *(const half8v*)&Ps[wv][c15 * 72 + 32 + q * 8];
            #pragma unroll
            for (int n = 0; n < 4; ++n) {
                #pragma unroll
                for (int r = 0; r < 4; ++r) O[n][r] *= al;
                half8v va0 = *(const half8v*)&Vt[0][(n * 16 + c15) * 32 + ksw];
                half8v va1 = *(const half8v*)&Vt[1][(n * 16 + c15) * 32 + ksw];
                O[n] = __builtin_amdgcn_mfma_f32_16x16x32_f16(va0, pb0, O[n], 0, 0, 0);
                O[n] = __builtin_amdgcn_mfma_f32_16x16x32_f16(va1, pb1, O[n], 0, 0, 0);
            }

            if (kt < ja) {
                __syncthreads();   // all waves done reading Vt (and Ks[bf])
                scatV();           // write V(kt+1) into single Vt buffer
                __syncthreads();   // Vt + async Ks[bf^1] (vmcnt drain) ready
            }
        }

        // epilogue: query = qbase+c15, d = n*16 + q*4 + r (4 contiguous -> 8B store)
        float rl = 1.0f / li;
        #pragma unroll
        for (int n = 0; n < 4; ++n) {
            half4v o4;
            #pragma unroll
            for (int r = 0; r < 4; ++r) o4[r] = (h16)(O[n][r] * rl);
            *(half4v*)(attn + ((size_t)(b * Sc + qbase + c15)) * Ec + h * HDc + n * 16 + q * 4) = o4;
        }
    }
}

// ---------------------------------------------------------------------------
extern "C" void kernel_launch(void* const* d_in, const int* in_sizes, int n_in,
                              void* d_out, int out_size, void* d_ws, size_t ws_size,
                              hipStream_t stream) {
    const float* x     = (const float*)d_in[0];
    const float* ln1_g = (const float*)d_in[1];
    const float* ln1_b = (const float*)d_in[2];
    const float* ln2_g = (const float*)d_in[3];
    const float* ln2_b = (const float*)d_in[4];
    const float* w_qkv = (const float*)d_in[5];
    const float* b_qkv = (const float*)d_in[6];
    const float* w_ao  = (const float*)d_in[7];
    const float* b_ao  = (const float*)d_in[8];
    const float* w_fc  = (const float*)d_in[9];
    const float* b_fc  = (const float*)d_in[10];
    const float* w_po  = (const float*)d_in[11];
    const float* b_po  = (const float*)d_in[12];
    float* out = (float*)d_out;

    // workspace (80 MB total):
    char* w = (char*)d_ws;
    h16* wqkv = (h16*)(w);             // 6 MB   (cvt4 outputs contiguous)
    h16* wao  = (h16*)(w + 6291456);   // 2 MB
    h16* wfc  = (h16*)(w + 8388608);   // 8 MB
    h16* wpo  = (h16*)(w + 16777216);  // 8 MB
    h16* hb   = (h16*)(w + 25165824);  // 8 MB  (fp16 LN out, reused)
    h16* qkv  = (h16*)(w + 33554432);  // 24 MB
    h16* attn = (h16*)(w + 58720256);  // 8 MB
    float* x1 = (float*)(w + 67108864);// 16 MB
    h16* ff   = qkv;                   // 32 MB alias over qkv+attn (dead)
    // PO split-K partials (all dead at PO time):
    //   P0 = w + 0        (wqkv+wao region, 8 MB)
    //   P1 = w + 8388608  (wfc region, 8 MB)
    //   P2 = w + 25165824 (hb region, 8 MB)

    dim3 blk(256);
    dim3 blk8(512);

    // fused weight converts fp32 -> fp16 (one launch)
    cvt4_kernel<<<dim3(12288), blk, 0, stream>>>(w_qkv, w_ao, w_fc, w_po, wqkv);

    // 1. hb = LN1(x)
    ln_kernel<<<dim3(ROWS), blk, 0, stream>>>(x, ln1_g, ln1_b, hb);
    // 2. qkv = hb @ w_qkv^T + b_qkv   (fp16 out)  [256^2 8-wave, read-ahead]
    gemm_8w<0, h16><<<dim3((ROWS / 256) * (3 * Ec / 256)), blk8, 0, stream>>>(
        hb, wqkv, b_qkv, nullptr, qkv, ROWS, 3 * Ec, Ec, Ec);
    // 3. attn = causal_flash_attention(qkv)   (fp16 out)  [paired q-tiles]
    attn_mfma<<<dim3(Bc * Hc, 16), blk, 0, stream>>>(qkv, attn);
    // 4. x1 = x + attn @ w_ao^T + b_ao  (fp32)   [1D grid, XCD swizzle, 4-deep]
    gemm_k64<1, float><<<dim3(512), blk, 0, stream>>>(
        attn, wao, b_ao, x, x1, ROWS, Ec, Ec);
    // 5. hb = LN2(x1)
    ln_kernel<<<dim3(ROWS), blk, 0, stream>>>(x1, ln2_g, ln2_b, hb);
    // 6. ff = gelu(hb @ w_fc^T + b_fc)  (fp16)   [256^2 8-wave, read-ahead]
    gemm_8w<2, h16><<<dim3((ROWS / 256) * (DFFc / 256)), blk8, 0, stream>>>(
        hb, wfc, b_fc, nullptr, ff, ROWS, DFFc, Ec, Ec);
    // 7a. PO split-K=4: splits 0-2 -> fp16 partials in ws, split 3 -> f32 out
    gemm_8w<3, float><<<dim3(256), blk8, 0, stream>>>(
        ff, wpo, b_po, (const float*)w, out, ROWS, Ec, 1024, DFFc);
    // 7b. out = out + x1 + b_po + P0 + P1 + P2
    red3_kernel<<<dim3(2048), blk, 0, stream>>>(
        (const h16*)w, (const h16*)(w + 8388608), (const h16*)(w + 25165824),
        x1, b_po, out);
}